// Round 1
// baseline (680.893 us; speedup 1.0000x reference)
//
#include <hip/hip_runtime.h>
#include <hip/hip_bf16.h>

#define N_NODES  50000
#define N_EDGES  800000
#define NDIM_IN  64
#define EDIMS    64
#define NDIM_OUT 128

typedef __bf16 bf16;
typedef bf16  bf16x8 __attribute__((ext_vector_type(8)));
typedef float f32x4  __attribute__((ext_vector_type(4)));

// ---------------------------------------------------------------------------
// Runtime dtype detection (harness dtype is ambiguous; we guard both ways).
// ---------------------------------------------------------------------------
__device__ __forceinline__ bool detect_f32(const void* nfeats) {
    const unsigned short* w = (const unsigned short*)nfeats;
    for (int i = 0; i < 64; i += 2) {
        const int e = (w[i] >> 7) & 0xFF;
        if (e < 100 || e > 134) return true;
    }
    return false;
}
__device__ __forceinline__ bool detect_i64(const int* p) {
    for (int i = 1; i < 64; i += 2) if (p[i] != 0) return false;
    return true;
}

__device__ __forceinline__ bf16x8 load8(const void* p, int off, bool f32) {
    if (f32) {
        const float* q = (const float*)p + off;
        const f32x4 a = *(const f32x4*)q;
        const f32x4 b = *(const f32x4*)(q + 4);
        bf16x8 r;
        #pragma unroll
        for (int u = 0; u < 4; ++u) { r[u] = (bf16)a[u]; r[4 + u] = (bf16)b[u]; }
        return r;
    }
    return *(const bf16x8*)((const bf16*)p + off);
}
__device__ __forceinline__ float loadf(const void* p, int i, bool f32) {
    return f32 ? ((const float*)p)[i] : (float)((const bf16*)p)[i];
}
__device__ __forceinline__ void storef(void* p, int i, float v, bool f32) {
    if (f32) ((float*)p)[i] = v; else ((bf16*)p)[i] = (bf16)v;
}

// ---------------------------------------------------------------------------
// CSR build: histogram over dst -> exclusive scan -> scatter edge ids.
// All int atomics land on a 200 KB L2-resident array; cheap.
// ---------------------------------------------------------------------------
__global__ __launch_bounds__(256) void hist_kernel(const int* __restrict__ dst,
                                                   int* __restrict__ cnt) {
    __shared__ int s_ish;
    if (threadIdx.x == 0) s_ish = detect_i64(dst) ? 1 : 0;
    __syncthreads();
    const int ish = s_ish;
    const int stride = gridDim.x * blockDim.x;
    for (int e = blockIdx.x * blockDim.x + threadIdx.x; e < N_EDGES; e += stride)
        atomicAdd(&cnt[dst[e << ish]], 1);
}

// Single-block exclusive scan of 50000 counts. Writes row_ptr[0..N] and
// resets cnt[] in place to the running cursor for the scatter pass.
__global__ __launch_bounds__(1024) void scan_kernel(int* __restrict__ cnt,
                                                    int* __restrict__ row_ptr) {
    __shared__ int sp[1024];
    const int t = threadIdx.x;
    const int PER = 49;                       // 1024*49 = 50176 >= 50000
    const int base = t * PER;
    int s = 0;
    for (int j = 0; j < PER; ++j) {
        const int i = base + j;
        if (i < N_NODES) s += cnt[i];
    }
    sp[t] = s;
    __syncthreads();
    for (int off = 1; off < 1024; off <<= 1) {   // Hillis-Steele inclusive
        const int v = (t >= off) ? sp[t - off] : 0;
        __syncthreads();
        sp[t] += v;
        __syncthreads();
    }
    int run = sp[t] - s;                      // exclusive prefix
    for (int j = 0; j < PER; ++j) {
        const int i = base + j;
        if (i < N_NODES) {
            const int c = cnt[i];
            row_ptr[i] = run;
            cnt[i] = run;                     // cursor start (aliases counts)
            run += c;
        }
    }
    if (t == 0) row_ptr[N_NODES] = N_EDGES;
}

__global__ __launch_bounds__(256) void scatter_kernel(const int* __restrict__ src,
                                                      const int* __restrict__ dst,
                                                      int* __restrict__ cursor,
                                                      int* __restrict__ eid,
                                                      int* __restrict__ srcs) {
    __shared__ int s_ish;
    if (threadIdx.x == 0) s_ish = detect_i64(dst) ? 1 : 0;
    __syncthreads();
    const int ish = s_ish;
    const int stride = gridDim.x * blockDim.x;
    for (int e = blockIdx.x * blockDim.x + threadIdx.x; e < N_EDGES; e += stride) {
        const int d = dst[e << ish];
        const int pos = atomicAdd(&cursor[d], 1);
        eid[pos]  = e;
        srcs[pos] = src[e << ish];
    }
}

// ---------------------------------------------------------------------------
// Fused message + aggregate (gather form): one wave per dst node.
// Tiles the node's CSR edge list in 16-edge MFMA tiles (same fragment layout
// as the verified atomic kernel), relu+bias per element, masks padded rows,
// reduces the 16 C-rows per column (2x shfl_xor, once per node), and writes
// h_neigh[v] exactly once with two coalesced 256 B stores. No fp atomics.
// ---------------------------------------------------------------------------
__global__ __launch_bounds__(256) void msg_agg_kernel(
    const void* __restrict__ nfeats,
    const void* __restrict__ efeats,
    const void* __restrict__ W_msg,
    const void* __restrict__ b_msg,
    const int*  __restrict__ row_ptr,
    const int*  __restrict__ eid,
    const int*  __restrict__ srcs,
    float*      __restrict__ h_neigh)
{
    __shared__ bf16 sWT[128 * 136];
    __shared__ int s_flags;

    const int tid = threadIdx.x;
    if (tid == 0) s_flags = detect_f32(nfeats) ? 1 : 0;
    __syncthreads();
    const bool f32 = (s_flags & 1) != 0;

    // stage W_msg^T: 128x128, 2048 8-elem chunks, 8 iters x 256 threads
    #pragma unroll
    for (int it = 0; it < 8; ++it) {
        const int task = it * 256 + tid;
        const int k = task >> 4;
        const int c = task & 15;
        const bf16x8 w = load8(W_msg, k * 128 + c * 8, f32);
        #pragma unroll
        for (int u = 0; u < 8; ++u) sWT[(c * 8 + u) * 136 + k] = w[u];
    }
    __syncthreads();

    const int wave = tid >> 6;
    const int lane = tid & 63;
    const int m    = lane & 15;   // edge row within tile / output col low bits
    const int quad = lane >> 4;   // k-group / C row group

    float bias[8];
    #pragma unroll
    for (int t = 0; t < 8; ++t) bias[t] = loadf(b_msg, t * 16 + m, f32);

    const int wstride = gridDim.x * 4;
    for (int v = blockIdx.x * 4 + wave; v < N_NODES; v += wstride) {
        const int beg = row_ptr[v];
        const int deg = row_ptr[v + 1] - beg;

        float hacc[8] = {0.f, 0.f, 0.f, 0.f, 0.f, 0.f, 0.f, 0.f};

        for (int T = 0; T * 16 < deg; ++T) {
            const int r0 = T * 16;
            const int sl = (r0 + m < deg) ? (beg + r0 + m) : beg;  // clamp pad rows
            const int s  = srcs[sl];
            const int e  = eid[sl];

            bf16x8 a[4];
            a[0] = load8(nfeats, s * 64 +      quad * 8, f32);   // k 0..31
            a[1] = load8(nfeats, s * 64 + 32 + quad * 8, f32);   // k 32..63
            a[2] = load8(efeats, e * 64 +      quad * 8, f32);   // k 64..95
            a[3] = load8(efeats, e * 64 + 32 + quad * 8, f32);   // k 96..127

            #pragma unroll
            for (int t = 0; t < 8; ++t) {
                f32x4 acc = {0.f, 0.f, 0.f, 0.f};
                const bf16* bp = sWT + (t * 16 + m) * 136 + quad * 8;
                #pragma unroll
                for (int kb = 0; kb < 4; ++kb)
                    acc = __builtin_amdgcn_mfma_f32_16x16x32_bf16(
                              a[kb], *(const bf16x8*)(bp + kb * 32), acc, 0, 0, 0);
                // relu+bias per element, mask padded C rows (row = quad*4+i),
                // accumulate per-lane partial column sums
                float part = 0.f;
                #pragma unroll
                for (int i = 0; i < 4; ++i) {
                    float val = acc[i] + bias[t];
                    val = val > 0.f ? val : 0.f;
                    if (r0 + quad * 4 + i < deg) part += val;
                }
                hacc[t] += part;
            }
        }

        // cross-quad column reduction, once per node (16 shuffles total)
        #pragma unroll
        for (int t = 0; t < 8; ++t) {
            float s = hacc[t];
            s += __shfl_xor(s, 16, 64);
            s += __shfl_xor(s, 32, 64);
            hacc[t] = s;
        }

        // lane = quad*16+m stores cols {lane, lane+64}: two coalesced 256B stores
        const float lo = quad < 2 ? (quad == 0 ? hacc[0] : hacc[1])
                                  : (quad == 2 ? hacc[2] : hacc[3]);
        const float hi = quad < 2 ? (quad == 0 ? hacc[4] : hacc[5])
                                  : (quad == 2 ? hacc[6] : hacc[7]);
        h_neigh[v * 128 + lane]      = lo;
        h_neigh[v * 128 + 64 + lane] = hi;
    }
}

// ---------------------------------------------------------------------------
// Fallback (verified previous version): per-edge messages + fp32 atomics.
// Used only if the workspace is too small for the CSR buffers.
// ---------------------------------------------------------------------------
__global__ __launch_bounds__(256) void edge_msg_kernel(
    const void* __restrict__ nfeats,
    const void* __restrict__ efeats,
    const void* __restrict__ W_msg,
    const void* __restrict__ b_msg,
    const int*  __restrict__ src,
    const int*  __restrict__ dst,
    float*      __restrict__ h_neigh)
{
    __shared__ bf16 sWT[128 * 136];
    __shared__ int s_flags;

    const int tid = threadIdx.x;
    if (tid == 0)
        s_flags = (detect_f32(nfeats) ? 1 : 0) | (detect_i64(dst) ? 2 : 0);
    __syncthreads();
    const bool f32 = (s_flags & 1) != 0;
    const int  ish = (s_flags & 2) ? 1 : 0;

    #pragma unroll
    for (int it = 0; it < 8; ++it) {
        const int task = it * 256 + tid;
        const int k = task >> 4;
        const int c = task & 15;
        const bf16x8 w = load8(W_msg, k * 128 + c * 8, f32);
        #pragma unroll
        for (int u = 0; u < 8; ++u) sWT[(c * 8 + u) * 136 + k] = w[u];
    }
    __syncthreads();

    const int wave = tid >> 6;
    const int lane = tid & 63;
    const int m    = lane & 15;
    const int quad = lane >> 4;

    const int nchunks = N_EDGES / 64;
    for (int chunk = blockIdx.x; chunk < nchunks; chunk += gridDim.x) {
        const int ebase = chunk * 64 + wave * 16;
        const int e_m   = ebase + m;
        const int s     = src[e_m << ish];

        bf16x8 a[4];
        a[0] = load8(nfeats, s   * 64 +      quad * 8, f32);
        a[1] = load8(nfeats, s   * 64 + 32 + quad * 8, f32);
        a[2] = load8(efeats, e_m * 64 +      quad * 8, f32);
        a[3] = load8(efeats, e_m * 64 + 32 + quad * 8, f32);

        int drow[4];
        #pragma unroll
        for (int i = 0; i < 4; ++i)
            drow[i] = dst[(ebase + quad * 4 + i) << ish] * 128;

        #pragma unroll
        for (int t = 0; t < 8; ++t) {
            f32x4 acc = {0.f, 0.f, 0.f, 0.f};
            const bf16* bp = sWT + (t * 16 + m) * 136 + quad * 8;
            #pragma unroll
            for (int kb = 0; kb < 4; ++kb)
                acc = __builtin_amdgcn_mfma_f32_16x16x32_bf16(
                          a[kb], *(const bf16x8*)(bp + kb * 32), acc, 0, 0, 0);
            const int   n    = t * 16 + m;
            const float bias = loadf(b_msg, n, f32);
            #pragma unroll
            for (int i = 0; i < 4; ++i) {
                float v = acc[i] + bias;
                v = v > 0.f ? v : 0.f;
                unsafeAtomicAdd(h_neigh + drow[i] + n, v);
            }
        }
    }
}

// ---------------------------------------------------------------------------
// Kernel B: out = relu([nfeats, h_neigh] @ W_apply + b_apply), K=192.
// (unchanged from verified version)
// ---------------------------------------------------------------------------
__global__ __launch_bounds__(256) void apply_kernel(
    const void*  __restrict__ nfeats,
    const float* __restrict__ h_neigh,
    const void*  __restrict__ W_apply,
    const void*  __restrict__ b_apply,
    void*        __restrict__ out)
{
    __shared__ bf16 sWT[128 * 200];
    __shared__ int s_flags;

    const int tid = threadIdx.x;
    if (tid == 0) s_flags = detect_f32(nfeats) ? 1 : 0;
    __syncthreads();
    const bool f32 = (s_flags & 1) != 0;

    #pragma unroll
    for (int it = 0; it < 12; ++it) {
        const int task = it * 256 + tid;
        const int k = task >> 4;
        const int c = task & 15;
        const bf16x8 w = load8(W_apply, k * 128 + c * 8, f32);
        #pragma unroll
        for (int u = 0; u < 8; ++u) sWT[(c * 8 + u) * 200 + k] = w[u];
    }
    __syncthreads();

    const int wave = tid >> 6;
    const int lane = tid & 63;
    const int m    = lane & 15;
    const int quad = lane >> 4;

    const int nchunks = (N_NODES + 63) / 64;
    for (int chunk = blockIdx.x; chunk < nchunks; chunk += gridDim.x) {
        const int nbase = chunk * 64 + wave * 16;
        const int nm  = nbase + m;
        const int nmc = nm < N_NODES ? nm : N_NODES - 1;

        bf16x8 a[6];
        a[0] = load8(nfeats, nmc * 64 +      quad * 8, f32);
        a[1] = load8(nfeats, nmc * 64 + 32 + quad * 8, f32);
        #pragma unroll
        for (int kb = 0; kb < 4; ++kb) {
            const float* hp = h_neigh + nmc * 128 + kb * 32 + quad * 8;
            const f32x4 p = *(const f32x4*)(hp);
            const f32x4 q = *(const f32x4*)(hp + 4);
            bf16x8 r;
            #pragma unroll
            for (int u = 0; u < 4; ++u) { r[u] = (bf16)p[u]; r[4 + u] = (bf16)q[u]; }
            a[2 + kb] = r;
        }

        #pragma unroll
        for (int t = 0; t < 8; ++t) {
            f32x4 acc = {0.f, 0.f, 0.f, 0.f};
            const bf16* bp = sWT + (t * 16 + m) * 200 + quad * 8;
            #pragma unroll
            for (int kb = 0; kb < 6; ++kb)
                acc = __builtin_amdgcn_mfma_f32_16x16x32_bf16(
                          a[kb], *(const bf16x8*)(bp + kb * 32), acc, 0, 0, 0);
            const int   n    = t * 16 + m;
            const float bias = loadf(b_apply, n, f32);
            #pragma unroll
            for (int i = 0; i < 4; ++i) {
                const int row = nbase + quad * 4 + i;
                if (row < N_NODES) {
                    float v = acc[i] + bias;
                    v = v > 0.f ? v : 0.f;
                    storef(out, row * 128 + n, v, f32);
                }
            }
        }
    }
}

extern "C" void kernel_launch(void* const* d_in, const int* in_sizes, int n_in,
                              void* d_out, int out_size, void* d_ws, size_t ws_size,
                              hipStream_t stream) {
    const void* nfeats  = d_in[0];
    const void* efeats  = d_in[1];
    const void* W_msg   = d_in[2];
    const void* b_msg   = d_in[3];
    const void* W_apply = d_in[4];
    const void* b_apply = d_in[5];
    const int*  src     = (const int*)d_in[6];
    const int*  dst     = (const int*)d_in[7];

    float* h_neigh = (float*)d_ws;                       // 25,600,000 B

    // CSR workspace layout (after h_neigh), 16B-aligned blocks:
    const size_t OFF_ROWPTR = 25600000;                  // 50001*4 -> 200,064
    const size_t OFF_CNT    = OFF_ROWPTR + 200064;       // counts, then cursor
    const size_t OFF_EID    = OFF_CNT + 200064;          // 800000*4
    const size_t OFF_SRCS   = OFF_EID + 3200000;         // 800000*4
    const size_t NEED       = OFF_SRCS + 3200000;        // 32,400,128 B

    if (ws_size >= NEED) {
        int* row_ptr = (int*)((char*)d_ws + OFF_ROWPTR);
        int* cnt     = (int*)((char*)d_ws + OFF_CNT);
        int* eid     = (int*)((char*)d_ws + OFF_EID);
        int* srcs    = (int*)((char*)d_ws + OFF_SRCS);

        hipMemsetAsync(cnt, 0, (size_t)N_NODES * sizeof(int), stream);
        hist_kernel<<<1024, 256, 0, stream>>>(dst, cnt);
        scan_kernel<<<1, 1024, 0, stream>>>(cnt, row_ptr);
        scatter_kernel<<<1024, 256, 0, stream>>>(src, dst, cnt, eid, srcs);
        msg_agg_kernel<<<1024, 256, 0, stream>>>(nfeats, efeats, W_msg, b_msg,
                                                 row_ptr, eid, srcs, h_neigh);
    } else {
        // fallback: previous verified atomic path
        hipMemsetAsync(h_neigh, 0, (size_t)N_NODES * NDIM_OUT * sizeof(float), stream);
        edge_msg_kernel<<<768, 256, 0, stream>>>(nfeats, efeats, W_msg, b_msg,
                                                 src, dst, h_neigh);
    }

    apply_kernel<<<512, 256, 0, stream>>>(nfeats, h_neigh, W_apply, b_apply, d_out);
}